// Round 3
// baseline (678.891 us; speedup 1.0000x reference)
//
#include <hip/hip_runtime.h>

#define B    32
#define N1   1024
#define FIN  128
#define NH   256
#define KP1  512
#define KP2  256
#define NCLS 10
#define MAXD 64
#define E1   1.7182818284590452f   // e^LAMB - 1, LAMB = 1.0

// ---------------- tiled GEMM: out[M,256] = A[M,KD] @ W[KD,256] ----------------
// block = BM rows x 256 cols; 256 threads = 32 col-threads (8 cols) x 8 row-threads (TM rows)
template<int KD, int BM, int TM>
__global__ void gemm_kernel(const float* __restrict__ A, const float* __restrict__ W,
                            float* __restrict__ out) {
    constexpr int KC = 16;
    __shared__ float sw[KC][256];
    __shared__ float sa[KC][BM];
    int m0 = blockIdx.x * BM;
    int tid = threadIdx.x;
    int ct = tid & 31, rt = tid >> 5;
    int c0 = ct * 8, r0 = rt * TM;
    float acc[TM][8] = {};
    for (int q0 = 0; q0 < KD; q0 += KC) {
        const float4* W4 = (const float4*)(W + q0 * 256);
        for (int i = tid; i < KC * 64; i += 256) {
            int q = i >> 6, c4 = i & 63;
            *(float4*)&sw[q][c4 * 4] = W4[q * 64 + c4];
        }
        const float4* A4 = (const float4*)A;
        for (int i = tid; i < BM * (KC / 4); i += 256) {
            int r = i / (KC / 4), j = i % (KC / 4);
            float4 v = A4[(size_t)(m0 + r) * (KD / 4) + q0 / 4 + j];
            sa[j * 4 + 0][r] = v.x; sa[j * 4 + 1][r] = v.y;
            sa[j * 4 + 2][r] = v.z; sa[j * 4 + 3][r] = v.w;
        }
        __syncthreads();
        #pragma unroll
        for (int q = 0; q < KC; ++q) {
            float wv[8], av[TM];
            *(float4*)&wv[0] = *(const float4*)&sw[q][c0];
            *(float4*)&wv[4] = *(const float4*)&sw[q][c0 + 4];
            #pragma unroll
            for (int j = 0; j < TM / 4; ++j)
                *(float4*)&av[j * 4] = *(const float4*)&sa[q][r0 + j * 4];
            #pragma unroll
            for (int r = 0; r < TM; ++r)
                #pragma unroll
                for (int c = 0; c < 8; ++c)
                    acc[r][c] += av[r] * wv[c];
        }
        __syncthreads();
    }
    for (int r = 0; r < TM; ++r) {
        *(float4*)&out[(size_t)(m0 + r0 + r) * 256 + c0] = *(float4*)&acc[r][0];
        *(float4*)&out[(size_t)(m0 + r0 + r) * 256 + c0 + 4] = *(float4*)&acc[r][4];
    }
}

// ---------------- CSR build: deterministic (column-ordered) ----------------
__global__ void csr_kernel(const float* __restrict__ adj, int* __restrict__ cnt,
                           int* __restrict__ nbr, float* __restrict__ dgi,
                           float* __restrict__ dia) {
    int row = blockIdx.x;                    // b*N1 + i
    const float* arow = adj + (size_t)row * N1;
    int t = threadIdx.x;                     // 256 threads, 4 cols each
    float4 v4 = ((const float4*)arow)[t];
    int loc[4];
    int c = 0;
    if (v4.x > 0.5f) loc[c++] = t * 4 + 0;
    if (v4.y > 0.5f) loc[c++] = t * 4 + 1;
    if (v4.z > 0.5f) loc[c++] = t * 4 + 2;
    if (v4.w > 0.5f) loc[c++] = t * 4 + 3;
    __shared__ int ps[256];
    ps[t] = c;
    __syncthreads();
    for (int s = 1; s < 256; s <<= 1) {
        int v = (t >= s) ? ps[t - s] : 0;
        __syncthreads();
        ps[t] += v;
        __syncthreads();
    }
    int total = ps[255];
    int off = ps[t] - c;                     // exclusive prefix
    for (int u = 0; u < c; ++u) {
        int p = off + u;
        if (p < MAXD) nbr[(size_t)row * MAXD + p] = loc[u];
    }
    if (t == 0) {
        cnt[row] = min(total, MAXD);
        dgi[row] = rsqrtf((float)total + 1.0f);            // deg of A=adj+I
        dia[row] = total > 0 ? 1.0f / (float)total : 0.0f; // deg of adj
    }
}

// ---------------- stage-1 GCN aggregate (sparse) ----------------
__global__ void gcn1_kernel(const float* __restrict__ t1, const int* __restrict__ cnt,
                            const int* __restrict__ nbr, const float* __restrict__ dgi,
                            const float* __restrict__ b1, float* __restrict__ h1) {
    int row = blockIdx.x;
    int b = row >> 10;
    int i = row & (N1 - 1);
    int bb = b << 10;
    int f = threadIdx.x;
    const float* tb = t1 + (size_t)b * N1 * NH;
    int n = cnt[row];
    __shared__ int lst[MAXD];
    __shared__ float sdg[MAXD];
    if (threadIdx.x < n) {
        int j = nbr[(size_t)row * MAXD + threadIdx.x];
        lst[threadIdx.x] = j;
        sdg[threadIdx.x] = dgi[bb + j];
    }
    __syncthreads();
    float a0 = 0.f, a1 = 0.f, a2 = 0.f, a3 = 0.f;
    int e = 0;
    for (; e + 4 <= n; e += 4) {
        a0 += sdg[e + 0] * tb[(size_t)lst[e + 0] * NH + f];
        a1 += sdg[e + 1] * tb[(size_t)lst[e + 1] * NH + f];
        a2 += sdg[e + 2] * tb[(size_t)lst[e + 2] * NH + f];
        a3 += sdg[e + 3] * tb[(size_t)lst[e + 3] * NH + f];
    }
    for (; e < n; ++e) a0 += sdg[e] * tb[(size_t)lst[e] * NH + f];
    float acc = (a0 + a1) + (a2 + a3);
    float di = dgi[row];
    float v = di * (acc + di * tb[(size_t)i * NH + f]) + b1[f];
    h1[(size_t)row * NH + f] = fmaxf(v, 0.f);
}

// ---------------- stage-1 info score (sparse) ----------------
__global__ void info1_kernel(const float* __restrict__ h1, const int* __restrict__ cnt,
                             const int* __restrict__ nbr, const float* __restrict__ dia,
                             float* __restrict__ sc) {
    int row = blockIdx.x;
    int b = row >> 10;
    int i = row & (N1 - 1);
    int f = threadIdx.x;
    const float* hb = h1 + (size_t)b * N1 * NH;
    int n = cnt[row];
    __shared__ int lst[MAXD];
    if (threadIdx.x < n) lst[threadIdx.x] = nbr[(size_t)row * MAXD + threadIdx.x];
    __syncthreads();
    float a0 = 0.f, a1 = 0.f, a2 = 0.f, a3 = 0.f;
    int e = 0;
    for (; e + 4 <= n; e += 4) {
        a0 += hb[(size_t)lst[e + 0] * NH + f];
        a1 += hb[(size_t)lst[e + 1] * NH + f];
        a2 += hb[(size_t)lst[e + 2] * NH + f];
        a3 += hb[(size_t)lst[e + 3] * NH + f];
    }
    for (; e < n; ++e) a0 += hb[(size_t)lst[e] * NH + f];
    float acc = (a0 + a1) + (a2 + a3);
    float v = fabsf(hb[(size_t)i * NH + f] - dia[row] * acc);
    __shared__ float red[256];
    red[f] = v;
    __syncthreads();
    for (int s = 128; s > 0; s >>= 1) {
        if (f < s) red[f] += red[f + s];
        __syncthreads();
    }
    if (f == 0) sc[row] = red[0];
}

// ---------------- top-k via bitonic sort (desc, tie: lower index first) ----------------
template<int NS, int KS, int NT, bool POS>
__global__ void topk_kernel(const float* __restrict__ sc, int* __restrict__ idxo,
                            int* __restrict__ pos) {
    int b = blockIdx.x;
    __shared__ float s[NS];
    __shared__ int id[NS];
    for (int i = threadIdx.x; i < NS; i += NT) { s[i] = sc[b * NS + i]; id[i] = i; }
    __syncthreads();
    for (int ksz = 2; ksz <= NS; ksz <<= 1) {
        for (int j = ksz >> 1; j > 0; j >>= 1) {
            for (int i = threadIdx.x; i < NS; i += NT) {
                int l = i ^ j;
                if (l > i) {
                    float si = s[i], sl = s[l];
                    int ii = id[i], il = id[l];
                    bool iBeforeL = (si > sl) || (si == sl && ii < il);
                    bool dirDesc = ((i & ksz) == 0);
                    if (dirDesc ? !iBeforeL : iBeforeL) {
                        s[i] = sl; s[l] = si; id[i] = il; id[l] = ii;
                    }
                }
            }
            __syncthreads();
        }
    }
    for (int t = threadIdx.x; t < KS; t += NT) idxo[b * KS + t] = id[t];
    if (POS)
        for (int t = threadIdx.x; t < NS; t += NT)
            pos[b * NS + id[t]] = (t < KS) ? t : -1;
}

// ---------------- gather pooled rows + attention dots ----------------
__global__ void gather_att_kernel(const float* __restrict__ h, const int* __restrict__ idx,
                                  const float* __restrict__ att, float* __restrict__ hk,
                                  float* __restrict__ lv, float* __restrict__ rv,
                                  int K, int Nsrc) {
    int g = blockIdx.x;              // b*K + p
    int b = g / K;
    int f = threadIdx.x;
    int src = idx[g];
    float v = h[((size_t)b * Nsrc + src) * NH + f];
    hk[(size_t)g * NH + f] = v;
    __shared__ float r1[256], r2[256];
    r1[f] = v * att[f];
    r2[f] = v * att[NH + f];
    __syncthreads();
    for (int s = 128; s > 0; s >>= 1) {
        if (f < s) { r1[f] += r1[f + s]; r2[f] += r2[f + s]; }
        __syncthreads();
    }
    if (f == 0) { lv[g] = r1[0]; rv[g] = r2[0]; }
}

// ---------------- v = exp(r - rowmax), V = sum v (per batch) ----------------
__global__ void vexp_kernel(const float* __restrict__ rv, float* __restrict__ v1,
                            float* __restrict__ V1) {
    int b = blockIdx.x;
    int t = threadIdx.x;             // 512
    __shared__ float red[512];
    float r = rv[b * KP1 + t];
    red[t] = r;
    __syncthreads();
    for (int s = 256; s > 0; s >>= 1) {
        if (t < s) red[t] = fmaxf(red[t], red[t + s]);
        __syncthreads();
    }
    float mx = red[0];
    __syncthreads();
    float v = expf(r - mx);
    v1[b * KP1 + t] = v;
    red[t] = v;
    __syncthreads();
    for (int s = 256; s > 0; s >>= 1) {
        if (t < s) red[t] += red[t + s];
        __syncthreads();
    }
    if (t == 0) V1[b] = red[0];
}

// ---------------- induced-subgraph CSR on idx1 + Z1 = V + E1*sum_nbr(v) ----------------
__global__ void knbr_kernel(const int* __restrict__ idx1, const int* __restrict__ cnt,
                            const int* __restrict__ nbr, const int* __restrict__ pos1,
                            const float* __restrict__ v1, const float* __restrict__ V1,
                            int* __restrict__ knbr, int* __restrict__ kcnt,
                            float* __restrict__ Z1) {
    int g = blockIdx.x;              // b*KP1 + p
    int b = g / KP1;
    int lane = threadIdx.x;          // 64 = one wave
    int ip = idx1[g];
    int n = cnt[b * N1 + ip];
    int q = -1;
    if (lane < n) {
        int j = nbr[(size_t)(b * N1 + ip) * MAXD + lane];
        q = pos1[b * N1 + j];
    }
    bool kept = q >= 0;
    unsigned long long mask = __ballot(kept);
    int off = __popcll(mask & ((1ull << lane) - 1ull));
    if (kept) knbr[(size_t)g * MAXD + off] = q;
    float s = kept ? v1[b * KP1 + q] : 0.f;
    for (int o = 32; o > 0; o >>= 1) s += __shfl_down(s, o);
    if (lane == 0) { kcnt[g] = __popcll(mask); Z1[g] = V1[b] + E1 * s; }
}

// ---------------- per-batch weighted column sum (partials over 8 chunks) ----------------
__global__ void wsum_kernel(const float* __restrict__ X, const float* __restrict__ v1,
                            float* __restrict__ wp) {
    int blk = blockIdx.x;            // b*8 + c
    int b = blk >> 3, c = blk & 7;
    int f = threadIdx.x;
    float a0 = 0.f, a1 = 0.f, a2 = 0.f, a3 = 0.f;
    for (int q = c * 64; q < c * 64 + 64; q += 4) {
        a0 += v1[b * KP1 + q + 0] * X[(size_t)(b * KP1 + q + 0) * NH + f];
        a1 += v1[b * KP1 + q + 1] * X[(size_t)(b * KP1 + q + 1) * NH + f];
        a2 += v1[b * KP1 + q + 2] * X[(size_t)(b * KP1 + q + 2) * NH + f];
        a3 += v1[b * KP1 + q + 3] * X[(size_t)(b * KP1 + q + 3) * NH + f];
    }
    wp[(size_t)blk * NH + f] = (a0 + a1) + (a2 + a3);
}

// ---------------- stage-2 GCN via factorized a1 ----------------
__global__ void gcn2_kernel(const float* __restrict__ t2, const float* __restrict__ wp,
                            const float* __restrict__ v1, const float* __restrict__ Z1,
                            const int* __restrict__ knbr, const int* __restrict__ kcnt,
                            const float* __restrict__ b2, float* __restrict__ h2) {
    int g = blockIdx.x;              // b*KP1 + p
    int b = g / KP1;
    int f = threadIdx.x;
    __shared__ int lst[MAXD];
    __shared__ float wv[MAXD];
    int n = kcnt[g];
    if (threadIdx.x < n) {
        int q = knbr[(size_t)g * MAXD + threadIdx.x];
        lst[threadIdx.x] = q;
        wv[threadIdx.x] = v1[b * KP1 + q];
    }
    __syncthreads();
    float a0 = 0.f, a1 = 0.f, a2 = 0.f, a3 = 0.f;
    int e = 0;
    for (; e + 4 <= n; e += 4) {
        a0 += wv[e + 0] * t2[(size_t)(b * KP1 + lst[e + 0]) * NH + f];
        a1 += wv[e + 1] * t2[(size_t)(b * KP1 + lst[e + 1]) * NH + f];
        a2 += wv[e + 2] * t2[(size_t)(b * KP1 + lst[e + 2]) * NH + f];
        a3 += wv[e + 3] * t2[(size_t)(b * KP1 + lst[e + 3]) * NH + f];
    }
    for (; e < n; ++e) a0 += wv[e] * t2[(size_t)(b * KP1 + lst[e]) * NH + f];
    float acc = (a0 + a1) + (a2 + a3);
    float w = 0.f;
    #pragma unroll
    for (int c = 0; c < 8; ++c) w += wp[(size_t)(b * 8 + c) * NH + f];
    float agg = (w + E1 * acc) / Z1[g];
    float tv = t2[(size_t)g * NH + f];
    h2[(size_t)g * NH + f] = fmaxf(0.5f * (agg + tv) + b2[f], 0.f);
}

// ---------------- stage-2 info score via factorized a1 ----------------
__global__ void info2_kernel(const float* __restrict__ h2, const float* __restrict__ wp,
                             const float* __restrict__ v1, const float* __restrict__ Z1,
                             const int* __restrict__ knbr, const int* __restrict__ kcnt,
                             float* __restrict__ sc) {
    int g = blockIdx.x;              // b*KP1 + p
    int b = g / KP1;
    int f = threadIdx.x;
    __shared__ int lst[MAXD];
    __shared__ float wv[MAXD];
    int n = kcnt[g];
    if (threadIdx.x < n) {
        int q = knbr[(size_t)g * MAXD + threadIdx.x];
        lst[threadIdx.x] = q;
        wv[threadIdx.x] = v1[b * KP1 + q];
    }
    __syncthreads();
    float a0 = 0.f, a1 = 0.f, a2 = 0.f, a3 = 0.f;
    int e = 0;
    for (; e + 4 <= n; e += 4) {
        a0 += wv[e + 0] * h2[(size_t)(b * KP1 + lst[e + 0]) * NH + f];
        a1 += wv[e + 1] * h2[(size_t)(b * KP1 + lst[e + 1]) * NH + f];
        a2 += wv[e + 2] * h2[(size_t)(b * KP1 + lst[e + 2]) * NH + f];
        a3 += wv[e + 3] * h2[(size_t)(b * KP1 + lst[e + 3]) * NH + f];
    }
    for (; e < n; ++e) a0 += wv[e] * h2[(size_t)(b * KP1 + lst[e]) * NH + f];
    float acc = (a0 + a1) + (a2 + a3);
    float w = 0.f;
    #pragma unroll
    for (int c = 0; c < 8; ++c) w += wp[(size_t)(b * 8 + c) * NH + f];
    float agg = (w + E1 * acc) / Z1[g];
    float val = fabsf(h2[(size_t)g * NH + f] - agg);
    __shared__ float red[256];
    red[f] = val;
    __syncthreads();
    for (int s = 128; s > 0; s >>= 1) {
        if (f < s) red[f] += red[f + s];
        __syncthreads();
    }
    if (f == 0) sc[g] = red[0];
}

// ---------------- materialize a2 = softmax(r2_q + a1k[p,q]) ----------------
__global__ void a2_kernel(const int* __restrict__ idx2, const float* __restrict__ rv,
                          const float* __restrict__ v1, const float* __restrict__ Z1,
                          const int* __restrict__ knbr, const int* __restrict__ kcnt,
                          float* __restrict__ a2) {
    int g = blockIdx.x;              // b*KP2 + p
    int b = g / KP2;
    int q = threadIdx.x;             // 256
    int p2 = idx2[g];                // position in [0,KP1)
    int gp = b * KP1 + p2;
    __shared__ unsigned char flag[KP1];
    flag[q] = 0; flag[q + 256] = 0;
    __syncthreads();
    int n = kcnt[gp];
    if (q < n) flag[knbr[(size_t)gp * MAXD + q]] = 1;
    __syncthreads();
    int q2 = idx2[b * KP2 + q];
    float a1k = v1[b * KP1 + q2] * (flag[q2] ? (1.f + E1) : 1.f) / Z1[gp];
    float z = rv[b * KP2 + q] + a1k;       // l_p cancels in softmax
    __shared__ float red[256];
    red[q] = z;
    __syncthreads();
    for (int s = 128; s > 0; s >>= 1) {
        if (q < s) red[q] = fmaxf(red[q], red[q + s]);
        __syncthreads();
    }
    float mx = red[0];
    __syncthreads();
    float e = expf(z - mx);
    red[q] = e;
    __syncthreads();
    for (int s = 128; s > 0; s >>= 1) {
        if (q < s) red[q] += red[q + s];
        __syncthreads();
    }
    a2[(size_t)g * KP2 + q] = e / red[0];
}

// ---------------- readout (parallel): rout[b,0:256]=relu(max), [256:512]=relu(mean) ----------------
template<int NROWS, bool INIT>
__global__ void readout_kernel(const float* __restrict__ h, float* __restrict__ rout) {
    int b = blockIdx.x;
    int f = threadIdx.x & 255, c = threadIdx.x >> 8;   // 1024 threads: 4 row-chunks
    const float* hb = h + (size_t)b * NROWS * NH;
    float mx = -1e30f, sm = 0.f;
    for (int p = c; p < NROWS; p += 4) {
        float v = hb[(size_t)p * NH + f];
        mx = fmaxf(mx, v);
        sm += v;
    }
    __shared__ float rm[4][256], rs[4][256];
    rm[c][f] = mx; rs[c][f] = sm;
    __syncthreads();
    if (c == 0) {
        #pragma unroll
        for (int j = 1; j < 4; ++j) { mx = fmaxf(mx, rm[j][f]); sm += rs[j][f]; }
        float rmv = fmaxf(mx, 0.f);
        float rav = fmaxf(sm * (1.0f / NROWS), 0.f);
        if (INIT) { rout[b * 512 + f] = rmv;  rout[b * 512 + NH + f] = rav; }
        else      { rout[b * 512 + f] += rmv; rout[b * 512 + NH + f] += rav; }
    }
}

// ---------------- fused stage-3: h3 = relu(0.5*(a2@t3 + t3) + b3) -> readout += ----------------
// grid B*8: block covers all 256 rows x 32-col slice. 256 thr = 8 ct (4 cols) x 32 rt (8 rows)
__global__ void gcn3_fused_kernel(const float* __restrict__ a2, const float* __restrict__ t3,
                                  const float* __restrict__ b3, float* __restrict__ rout) {
    constexpr int KC = 16;
    __shared__ float sa[KC][256];
    __shared__ float st[KC][32];
    int b = blockIdx.x >> 3;
    int cb = (blockIdx.x & 7) * 32;
    int tid = threadIdx.x;
    int ct = tid & 7, rt = tid >> 3;
    int c0 = cb + ct * 4, r0 = rt * 8;
    const float* ab = a2 + (size_t)b * KP2 * KP2;
    const float* tb = t3 + (size_t)b * KP2 * NH;
    float acc[8][4] = {};
    for (int q0 = 0; q0 < KP2; q0 += KC) {
        const float4* A4 = (const float4*)ab;
        for (int i = tid; i < 256 * (KC / 4); i += 256) {
            int r = i >> 2, j = i & 3;
            float4 v = A4[(size_t)r * 64 + q0 / 4 + j];
            sa[j * 4 + 0][r] = v.x; sa[j * 4 + 1][r] = v.y;
            sa[j * 4 + 2][r] = v.z; sa[j * 4 + 3][r] = v.w;
        }
        if (tid < KC * 8) {
            int q = tid >> 3, c4 = tid & 7;
            *(float4*)&st[q][c4 * 4] = *(const float4*)&tb[(size_t)(q0 + q) * NH + cb + c4 * 4];
        }
        __syncthreads();
        #pragma unroll
        for (int q = 0; q < KC; ++q) {
            float tv[4], av[8];
            *(float4*)&tv[0] = *(const float4*)&st[q][ct * 4];
            *(float4*)&av[0] = *(const float4*)&sa[q][r0];
            *(float4*)&av[4] = *(const float4*)&sa[q][r0 + 4];
            #pragma unroll
            for (int r = 0; r < 8; ++r)
                #pragma unroll
                for (int c = 0; c < 4; ++c)
                    acc[r][c] += av[r] * tv[c];
        }
        __syncthreads();
    }
    float bv[4];
    *(float4*)&bv[0] = *(const float4*)&b3[c0];
    float mx[4] = {-1e30f, -1e30f, -1e30f, -1e30f}, sm[4] = {};
    for (int r = 0; r < 8; ++r) {
        float4 t4 = *(const float4*)&tb[(size_t)(r0 + r) * NH + c0];
        float tvv[4] = {t4.x, t4.y, t4.z, t4.w};
        #pragma unroll
        for (int c = 0; c < 4; ++c) {
            float h = fmaxf(0.5f * (acc[r][c] + tvv[c]) + bv[c], 0.f);
            mx[c] = fmaxf(mx[c], h);
            sm[c] += h;
        }
    }
    __shared__ float rmx[32][33], rsm[32][33];
    #pragma unroll
    for (int c = 0; c < 4; ++c) { rmx[ct * 4 + c][rt] = mx[c]; rsm[ct * 4 + c][rt] = sm[c]; }
    __syncthreads();
    if (tid < 32) {
        float m = -1e30f, s = 0.f;
        for (int r = 0; r < 32; ++r) { m = fmaxf(m, rmx[tid][r]); s += rsm[tid][r]; }
        rout[b * 512 + cb + tid] += fmaxf(m, 0.f);
        rout[b * 512 + NH + cb + tid] += fmaxf(s * (1.f / KP2), 0.f);
    }
}

// ---------------- final linear ----------------
__global__ void final_kernel(const float* __restrict__ rout, const float* __restrict__ Wlin,
                             const float* __restrict__ blin, float* __restrict__ out) {
    int b = blockIdx.x;
    int c = threadIdx.x;
    if (c < NCLS) {
        float acc = blin[c];
        for (int fidx = 0; fidx < 512; ++fidx)
            acc += rout[b * 512 + fidx] * Wlin[fidx * NCLS + c];
        out[b * NCLS + c] = acc;
    }
}

extern "C" void kernel_launch(void* const* d_in, const int* in_sizes, int n_in,
                              void* d_out, int out_size, void* d_ws, size_t ws_size,
                              hipStream_t stream) {
    const float* x    = (const float*)d_in[0];
    const float* adj  = (const float*)d_in[1];
    const float* W1   = (const float*)d_in[2];
    const float* b1   = (const float*)d_in[3];
    const float* W2   = (const float*)d_in[4];
    const float* b2   = (const float*)d_in[5];
    const float* W3   = (const float*)d_in[6];
    const float* b3   = (const float*)d_in[7];
    const float* att1 = (const float*)d_in[8];
    const float* att2 = (const float*)d_in[9];
    const float* Wlin = (const float*)d_in[10];
    const float* blin = (const float*)d_in[11];
    float* out = (float*)d_out;

    float* fws = (float*)d_ws;
    float* t1  = fws;                        // 8,388,608 floats
    float* h1  = t1 + 8388608;               // 8,388,608
    float* hk  = h1 + 8388608;               // 4,194,304
    float* dgi = hk + 4194304;               // 32768
    float* dia = dgi + 32768;
    float* sc  = dia + 32768;
    float* lv  = sc + 32768;                 // 16384
    float* rv  = lv + 16384;                 // 16384
    float* rout = rv + 16384;                // 16384
    float* v1  = rout + 16384;               // 16384
    float* V1  = v1 + 16384;                 // 64 (padded)
    float* Z1  = V1 + 64;                    // 16384
    float* wp  = Z1 + 16384;                 // 32*8*256 = 65536
    int* cnt  = (int*)(wp + 65536);          // 32768
    int* nbr  = cnt + 32768;                 // 32768*64 = 2,097,152
    int* idx1 = nbr + 32768 * MAXD;          // 16384
    int* idx2 = idx1 + 16384;                // 8192
    int* pos1 = idx2 + 8192;                 // 32768
    // aliases (lifetime-disjoint reuse)
    float* t2   = h1;                        // stage-2 XW   [B*KP1*NH]
    float* h2   = h1 + 4194304;              // stage-2 hidden
    float* h2k  = hk;                        // stage-2 pooled rows
    float* a2   = t1;                        // [B*KP2*KP2] = 2,097,152 (t1 dead after gcn1)
    float* t3   = t1 + 2097152;              // 2,097,152
    int*   knbr = (int*)(t1 + 6291456);      // 16384*64 = 1,048,576 ints
    int*   kcnt = knbr + 16384 * MAXD;       // 16384

    // ---- stage 1 (sparse binary graph) ----
    gemm_kernel<FIN, 64, 8><<<512, 256, 0, stream>>>(x, W1, t1);
    csr_kernel<<<B * N1, 256, 0, stream>>>(adj, cnt, nbr, dgi, dia);
    gcn1_kernel<<<B * N1, 256, 0, stream>>>(t1, cnt, nbr, dgi, b1, h1);
    info1_kernel<<<B * N1, 256, 0, stream>>>(h1, cnt, nbr, dia, sc);
    topk_kernel<N1, KP1, 512, true><<<B, 512, 0, stream>>>(sc, idx1, pos1);
    gather_att_kernel<<<B * KP1, 256, 0, stream>>>(h1, idx1, att1, hk, lv, rv, KP1, N1);
    readout_kernel<KP1, true><<<B, 1024, 0, stream>>>(hk, rout);

    // ---- pool-1 factorization: a1[p,q] = v_q*(1+E1*adjk)/Z_p ----
    vexp_kernel<<<B, 512, 0, stream>>>(rv, v1, V1);
    knbr_kernel<<<B * KP1, 64, 0, stream>>>(idx1, cnt, nbr, pos1, v1, V1, knbr, kcnt, Z1);

    // ---- stage 2 (factorized a1) ----
    gemm_kernel<NH, 64, 8><<<256, 256, 0, stream>>>(hk, W2, t2);
    wsum_kernel<<<B * 8, 256, 0, stream>>>(t2, v1, wp);
    gcn2_kernel<<<B * KP1, 256, 0, stream>>>(t2, wp, v1, Z1, knbr, kcnt, b2, h2);
    wsum_kernel<<<B * 8, 256, 0, stream>>>(h2, v1, wp);
    info2_kernel<<<B * KP1, 256, 0, stream>>>(h2, wp, v1, Z1, knbr, kcnt, sc);
    topk_kernel<KP1, KP2, 256, false><<<B, 256, 0, stream>>>(sc, idx2, nullptr);
    gather_att_kernel<<<B * KP2, 256, 0, stream>>>(h2, idx2, att2, h2k, lv, rv, KP2, KP1);
    readout_kernel<KP2, false><<<B, 1024, 0, stream>>>(h2k, rout);
    a2_kernel<<<B * KP2, 256, 0, stream>>>(idx2, rv, v1, Z1, knbr, kcnt, a2);

    // ---- stage 3 (fused dense GCN + readout) ----
    gemm_kernel<NH, 32, 4><<<256, 256, 0, stream>>>(h2k, W3, t3);
    gcn3_fused_kernel<<<B * 8, 256, 0, stream>>>(a2, t3, b3, rout);

    // ---- classifier ----
    final_kernel<<<B, 64, 0, stream>>>(rout, Wlin, blin, out);
}

// Round 4
// 540.292 us; speedup vs baseline: 1.2565x; 1.2565x over previous
//
#include <hip/hip_runtime.h>

#define B    32
#define N1   1024
#define FIN  128
#define NH   256
#define KP1  512
#define KP2  256
#define NCLS 10
#define MAXD 64
#define E1   1.7182818284590452f   // e^LAMB - 1, LAMB = 1.0

// ---------------- tiled GEMM: out[M,256] = A[M,KD] @ W[KD,256] ----------------
// block = BM rows x 256 cols; 256 threads = 32 col-threads (8 cols) x 8 row-threads (TM rows)
template<int KD, int BM, int TM>
__global__ __launch_bounds__(256, 2)
void gemm_kernel(const float* __restrict__ A, const float* __restrict__ W,
                 float* __restrict__ out) {
    constexpr int KC = 16;
    constexpr int SAP = BM + 4;              // padded stride: bank-conflict-free staging
    __shared__ float sw[KC][256];
    __shared__ float sa[KC][SAP];
    int m0 = blockIdx.x * BM;
    int tid = threadIdx.x;
    int ct = tid & 31, rt = tid >> 5;
    int c0 = ct * 8, r0 = rt * TM;
    float acc[TM][8] = {};
    for (int q0 = 0; q0 < KD; q0 += KC) {
        const float4* W4 = (const float4*)(W + q0 * 256);
        for (int i = tid; i < KC * 64; i += 256) {
            int q = i >> 6, c4 = i & 63;
            *(float4*)&sw[q][c4 * 4] = W4[q * 64 + c4];
        }
        const float4* A4 = (const float4*)A;
        for (int i = tid; i < BM * (KC / 4); i += 256) {
            int r = i / (KC / 4), j = i % (KC / 4);
            float4 v = A4[(size_t)(m0 + r) * (KD / 4) + q0 / 4 + j];
            sa[j * 4 + 0][r] = v.x; sa[j * 4 + 1][r] = v.y;
            sa[j * 4 + 2][r] = v.z; sa[j * 4 + 3][r] = v.w;
        }
        __syncthreads();
        #pragma unroll
        for (int q = 0; q < KC; ++q) {
            float wv[8], av[TM];
            *(float4*)&wv[0] = *(const float4*)&sw[q][c0];
            *(float4*)&wv[4] = *(const float4*)&sw[q][c0 + 4];
            #pragma unroll
            for (int j = 0; j < TM / 4; ++j)
                *(float4*)&av[j * 4] = *(const float4*)&sa[q][r0 + j * 4];
            #pragma unroll
            for (int r = 0; r < TM; ++r)
                #pragma unroll
                for (int c = 0; c < 8; ++c)
                    acc[r][c] += av[r] * wv[c];
        }
        __syncthreads();
    }
    for (int r = 0; r < TM; ++r) {
        *(float4*)&out[(size_t)(m0 + r0 + r) * 256 + c0] = *(float4*)&acc[r][0];
        *(float4*)&out[(size_t)(m0 + r0 + r) * 256 + c0 + 4] = *(float4*)&acc[r][4];
    }
}

// ---------------- CSR build: deterministic (column-ordered) ----------------
__global__ __launch_bounds__(256)
void csr_kernel(const float* __restrict__ adj, int* __restrict__ cnt,
                int* __restrict__ nbr, float* __restrict__ dgi,
                float* __restrict__ dia) {
    int row = blockIdx.x;                    // b*N1 + i
    const float* arow = adj + (size_t)row * N1;
    int t = threadIdx.x;                     // 256 threads, 4 cols each
    float4 v4 = ((const float4*)arow)[t];
    int loc[4];
    int c = 0;
    if (v4.x > 0.5f) loc[c++] = t * 4 + 0;
    if (v4.y > 0.5f) loc[c++] = t * 4 + 1;
    if (v4.z > 0.5f) loc[c++] = t * 4 + 2;
    if (v4.w > 0.5f) loc[c++] = t * 4 + 3;
    __shared__ int ps[256];
    ps[t] = c;
    __syncthreads();
    for (int s = 1; s < 256; s <<= 1) {
        int v = (t >= s) ? ps[t - s] : 0;
        __syncthreads();
        ps[t] += v;
        __syncthreads();
    }
    int total = ps[255];
    int off = ps[t] - c;                     // exclusive prefix
    for (int u = 0; u < c; ++u) {
        int p = off + u;
        if (p < MAXD) nbr[(size_t)row * MAXD + p] = loc[u];
    }
    if (t == 0) {
        cnt[row] = min(total, MAXD);
        dgi[row] = rsqrtf((float)total + 1.0f);            // deg of A=adj+I
        dia[row] = total > 0 ? 1.0f / (float)total : 0.0f; // deg of adj
    }
}

// ---------------- stage-1 GCN aggregate (sparse) ----------------
__global__ __launch_bounds__(256)
void gcn1_kernel(const float* __restrict__ t1, const int* __restrict__ cnt,
                 const int* __restrict__ nbr, const float* __restrict__ dgi,
                 const float* __restrict__ b1, float* __restrict__ h1) {
    int row = blockIdx.x;
    int b = row >> 10;
    int i = row & (N1 - 1);
    int bb = b << 10;
    int f = threadIdx.x;
    const float* tb = t1 + (size_t)b * N1 * NH;
    int n = cnt[row];
    __shared__ int lst[MAXD];
    __shared__ float sdg[MAXD];
    if (threadIdx.x < n) {
        int j = nbr[(size_t)row * MAXD + threadIdx.x];
        lst[threadIdx.x] = j;
        sdg[threadIdx.x] = dgi[bb + j];
    }
    __syncthreads();
    float a0 = 0.f, a1 = 0.f, a2 = 0.f, a3 = 0.f;
    int e = 0;
    for (; e + 4 <= n; e += 4) {
        a0 += sdg[e + 0] * tb[(size_t)lst[e + 0] * NH + f];
        a1 += sdg[e + 1] * tb[(size_t)lst[e + 1] * NH + f];
        a2 += sdg[e + 2] * tb[(size_t)lst[e + 2] * NH + f];
        a3 += sdg[e + 3] * tb[(size_t)lst[e + 3] * NH + f];
    }
    for (; e < n; ++e) a0 += sdg[e] * tb[(size_t)lst[e] * NH + f];
    float acc = (a0 + a1) + (a2 + a3);
    float di = dgi[row];
    float v = di * (acc + di * tb[(size_t)i * NH + f]) + b1[f];
    h1[(size_t)row * NH + f] = fmaxf(v, 0.f);
}

// ---------------- stage-1 info score (sparse) ----------------
__global__ __launch_bounds__(256)
void info1_kernel(const float* __restrict__ h1, const int* __restrict__ cnt,
                  const int* __restrict__ nbr, const float* __restrict__ dia,
                  float* __restrict__ sc) {
    int row = blockIdx.x;
    int b = row >> 10;
    int i = row & (N1 - 1);
    int f = threadIdx.x;
    const float* hb = h1 + (size_t)b * N1 * NH;
    int n = cnt[row];
    __shared__ int lst[MAXD];
    if (threadIdx.x < n) lst[threadIdx.x] = nbr[(size_t)row * MAXD + threadIdx.x];
    __syncthreads();
    float a0 = 0.f, a1 = 0.f, a2 = 0.f, a3 = 0.f;
    int e = 0;
    for (; e + 4 <= n; e += 4) {
        a0 += hb[(size_t)lst[e + 0] * NH + f];
        a1 += hb[(size_t)lst[e + 1] * NH + f];
        a2 += hb[(size_t)lst[e + 2] * NH + f];
        a3 += hb[(size_t)lst[e + 3] * NH + f];
    }
    for (; e < n; ++e) a0 += hb[(size_t)lst[e] * NH + f];
    float acc = (a0 + a1) + (a2 + a3);
    float v = fabsf(hb[(size_t)i * NH + f] - dia[row] * acc);
    __shared__ float red[256];
    red[f] = v;
    __syncthreads();
    for (int s = 128; s > 0; s >>= 1) {
        if (f < s) red[f] += red[f + s];
        __syncthreads();
    }
    if (f == 0) sc[row] = red[0];
}

// ---------------- top-k via bitonic sort (desc, tie: lower index first) ----------------
template<int NS, int KS, int NT, bool POS>
__global__ __launch_bounds__(512)
void topk_kernel(const float* __restrict__ sc, int* __restrict__ idxo,
                 int* __restrict__ pos) {
    int b = blockIdx.x;
    __shared__ float s[NS];
    __shared__ int id[NS];
    for (int i = threadIdx.x; i < NS; i += NT) { s[i] = sc[b * NS + i]; id[i] = i; }
    __syncthreads();
    for (int ksz = 2; ksz <= NS; ksz <<= 1) {
        for (int j = ksz >> 1; j > 0; j >>= 1) {
            for (int i = threadIdx.x; i < NS; i += NT) {
                int l = i ^ j;
                if (l > i) {
                    float si = s[i], sl = s[l];
                    int ii = id[i], il = id[l];
                    bool iBeforeL = (si > sl) || (si == sl && ii < il);
                    bool dirDesc = ((i & ksz) == 0);
                    if (dirDesc ? !iBeforeL : iBeforeL) {
                        s[i] = sl; s[l] = si; id[i] = il; id[l] = ii;
                    }
                }
            }
            __syncthreads();
        }
    }
    for (int t = threadIdx.x; t < KS; t += NT) idxo[b * KS + t] = id[t];
    if (POS)
        for (int t = threadIdx.x; t < NS; t += NT)
            pos[b * NS + id[t]] = (t < KS) ? t : -1;
}

// ---------------- gather pooled rows + attention dots ----------------
__global__ __launch_bounds__(256)
void gather_att_kernel(const float* __restrict__ h, const int* __restrict__ idx,
                       const float* __restrict__ att, float* __restrict__ hk,
                       float* __restrict__ lv, float* __restrict__ rv,
                       int K, int Nsrc) {
    int g = blockIdx.x;              // b*K + p
    int b = g / K;
    int f = threadIdx.x;
    int src = idx[g];
    float v = h[((size_t)b * Nsrc + src) * NH + f];
    hk[(size_t)g * NH + f] = v;
    __shared__ float r1[256], r2[256];
    r1[f] = v * att[f];
    r2[f] = v * att[NH + f];
    __syncthreads();
    for (int s = 128; s > 0; s >>= 1) {
        if (f < s) { r1[f] += r1[f + s]; r2[f] += r2[f + s]; }
        __syncthreads();
    }
    if (f == 0) { lv[g] = r1[0]; rv[g] = r2[0]; }
}

// ---------------- v = exp(r - rowmax), V = sum v (per batch) ----------------
__global__ __launch_bounds__(512)
void vexp_kernel(const float* __restrict__ rv, float* __restrict__ v1,
                 float* __restrict__ V1) {
    int b = blockIdx.x;
    int t = threadIdx.x;             // 512
    __shared__ float red[512];
    float r = rv[b * KP1 + t];
    red[t] = r;
    __syncthreads();
    for (int s = 256; s > 0; s >>= 1) {
        if (t < s) red[t] = fmaxf(red[t], red[t + s]);
        __syncthreads();
    }
    float mx = red[0];
    __syncthreads();
    float v = expf(r - mx);
    v1[b * KP1 + t] = v;
    red[t] = v;
    __syncthreads();
    for (int s = 256; s > 0; s >>= 1) {
        if (t < s) red[t] += red[t + s];
        __syncthreads();
    }
    if (t == 0) V1[b] = red[0];
}

// ---------------- induced-subgraph CSR on idx1 + Z1 = V + E1*sum_nbr(v) ----------------
__global__ __launch_bounds__(64)
void knbr_kernel(const int* __restrict__ idx1, const int* __restrict__ cnt,
                 const int* __restrict__ nbr, const int* __restrict__ pos1,
                 const float* __restrict__ v1, const float* __restrict__ V1,
                 int* __restrict__ knbr, int* __restrict__ kcnt,
                 float* __restrict__ Z1) {
    int g = blockIdx.x;              // b*KP1 + p
    int b = g / KP1;
    int lane = threadIdx.x;          // 64 = one wave
    int ip = idx1[g];
    int n = cnt[b * N1 + ip];
    int q = -1;
    if (lane < n) {
        int j = nbr[(size_t)(b * N1 + ip) * MAXD + lane];
        q = pos1[b * N1 + j];
    }
    bool kept = q >= 0;
    unsigned long long mask = __ballot(kept);
    int off = __popcll(mask & ((1ull << lane) - 1ull));
    if (kept) knbr[(size_t)g * MAXD + off] = q;
    float s = kept ? v1[b * KP1 + q] : 0.f;
    for (int o = 32; o > 0; o >>= 1) s += __shfl_down(s, o);
    if (lane == 0) { kcnt[g] = __popcll(mask); Z1[g] = V1[b] + E1 * s; }
}

// ---------------- per-batch weighted column sum (partials over 8 chunks) ----------------
__global__ __launch_bounds__(256)
void wsum_kernel(const float* __restrict__ X, const float* __restrict__ v1,
                 float* __restrict__ wp) {
    int blk = blockIdx.x;            // b*8 + c
    int b = blk >> 3, c = blk & 7;
    int f = threadIdx.x;
    float a0 = 0.f, a1 = 0.f, a2 = 0.f, a3 = 0.f;
    for (int q = c * 64; q < c * 64 + 64; q += 4) {
        a0 += v1[b * KP1 + q + 0] * X[(size_t)(b * KP1 + q + 0) * NH + f];
        a1 += v1[b * KP1 + q + 1] * X[(size_t)(b * KP1 + q + 1) * NH + f];
        a2 += v1[b * KP1 + q + 2] * X[(size_t)(b * KP1 + q + 2) * NH + f];
        a3 += v1[b * KP1 + q + 3] * X[(size_t)(b * KP1 + q + 3) * NH + f];
    }
    wp[(size_t)blk * NH + f] = (a0 + a1) + (a2 + a3);
}

// ---------------- stage-2 GCN via factorized a1 ----------------
__global__ __launch_bounds__(256)
void gcn2_kernel(const float* __restrict__ t2, const float* __restrict__ wp,
                 const float* __restrict__ v1, const float* __restrict__ Z1,
                 const int* __restrict__ knbr, const int* __restrict__ kcnt,
                 const float* __restrict__ b2, float* __restrict__ h2) {
    int g = blockIdx.x;              // b*KP1 + p
    int b = g / KP1;
    int f = threadIdx.x;
    __shared__ int lst[MAXD];
    __shared__ float wv[MAXD];
    int n = kcnt[g];
    if (threadIdx.x < n) {
        int q = knbr[(size_t)g * MAXD + threadIdx.x];
        lst[threadIdx.x] = q;
        wv[threadIdx.x] = v1[b * KP1 + q];
    }
    __syncthreads();
    float a0 = 0.f, a1 = 0.f, a2 = 0.f, a3 = 0.f;
    int e = 0;
    for (; e + 4 <= n; e += 4) {
        a0 += wv[e + 0] * t2[(size_t)(b * KP1 + lst[e + 0]) * NH + f];
        a1 += wv[e + 1] * t2[(size_t)(b * KP1 + lst[e + 1]) * NH + f];
        a2 += wv[e + 2] * t2[(size_t)(b * KP1 + lst[e + 2]) * NH + f];
        a3 += wv[e + 3] * t2[(size_t)(b * KP1 + lst[e + 3]) * NH + f];
    }
    for (; e < n; ++e) a0 += wv[e] * t2[(size_t)(b * KP1 + lst[e]) * NH + f];
    float acc = (a0 + a1) + (a2 + a3);
    float w = 0.f;
    #pragma unroll
    for (int c = 0; c < 8; ++c) w += wp[(size_t)(b * 8 + c) * NH + f];
    float agg = (w + E1 * acc) / Z1[g];
    float tv = t2[(size_t)g * NH + f];
    h2[(size_t)g * NH + f] = fmaxf(0.5f * (agg + tv) + b2[f], 0.f);
}

// ---------------- stage-2 info score via factorized a1 ----------------
__global__ __launch_bounds__(256)
void info2_kernel(const float* __restrict__ h2, const float* __restrict__ wp,
                  const float* __restrict__ v1, const float* __restrict__ Z1,
                  const int* __restrict__ knbr, const int* __restrict__ kcnt,
                  float* __restrict__ sc) {
    int g = blockIdx.x;              // b*KP1 + p
    int b = g / KP1;
    int f = threadIdx.x;
    __shared__ int lst[MAXD];
    __shared__ float wv[MAXD];
    int n = kcnt[g];
    if (threadIdx.x < n) {
        int q = knbr[(size_t)g * MAXD + threadIdx.x];
        lst[threadIdx.x] = q;
        wv[threadIdx.x] = v1[b * KP1 + q];
    }
    __syncthreads();
    float a0 = 0.f, a1 = 0.f, a2 = 0.f, a3 = 0.f;
    int e = 0;
    for (; e + 4 <= n; e += 4) {
        a0 += wv[e + 0] * h2[(size_t)(b * KP1 + lst[e + 0]) * NH + f];
        a1 += wv[e + 1] * h2[(size_t)(b * KP1 + lst[e + 1]) * NH + f];
        a2 += wv[e + 2] * h2[(size_t)(b * KP1 + lst[e + 2]) * NH + f];
        a3 += wv[e + 3] * h2[(size_t)(b * KP1 + lst[e + 3]) * NH + f];
    }
    for (; e < n; ++e) a0 += wv[e] * h2[(size_t)(b * KP1 + lst[e]) * NH + f];
    float acc = (a0 + a1) + (a2 + a3);
    float w = 0.f;
    #pragma unroll
    for (int c = 0; c < 8; ++c) w += wp[(size_t)(b * 8 + c) * NH + f];
    float agg = (w + E1 * acc) / Z1[g];
    float val = fabsf(h2[(size_t)g * NH + f] - agg);
    __shared__ float red[256];
    red[f] = val;
    __syncthreads();
    for (int s = 128; s > 0; s >>= 1) {
        if (f < s) red[f] += red[f + s];
        __syncthreads();
    }
    if (f == 0) sc[g] = red[0];
}

// ---------------- materialize a2 = softmax(r2_q + a1k[p,q]) ----------------
__global__ __launch_bounds__(256)
void a2_kernel(const int* __restrict__ idx2, const float* __restrict__ rv,
               const float* __restrict__ v1, const float* __restrict__ Z1,
               const int* __restrict__ knbr, const int* __restrict__ kcnt,
               float* __restrict__ a2) {
    int g = blockIdx.x;              // b*KP2 + p
    int b = g / KP2;
    int q = threadIdx.x;             // 256
    int p2 = idx2[g];                // position in [0,KP1)
    int gp = b * KP1 + p2;
    __shared__ unsigned char flag[KP1];
    flag[q] = 0; flag[q + 256] = 0;
    __syncthreads();
    int n = kcnt[gp];
    if (q < n) flag[knbr[(size_t)gp * MAXD + q]] = 1;
    __syncthreads();
    int q2 = idx2[b * KP2 + q];
    float a1k = v1[b * KP1 + q2] * (flag[q2] ? (1.f + E1) : 1.f) / Z1[gp];
    float z = rv[b * KP2 + q] + a1k;       // l_p cancels in softmax
    __shared__ float red[256];
    red[q] = z;
    __syncthreads();
    for (int s = 128; s > 0; s >>= 1) {
        if (q < s) red[q] = fmaxf(red[q], red[q + s]);
        __syncthreads();
    }
    float mx = red[0];
    __syncthreads();
    float e = expf(z - mx);
    red[q] = e;
    __syncthreads();
    for (int s = 128; s > 0; s >>= 1) {
        if (q < s) red[q] += red[q + s];
        __syncthreads();
    }
    a2[(size_t)g * KP2 + q] = e / red[0];
}

// ---------------- readout (parallel): rout[b,0:256]=relu(max), [256:512]=relu(mean) ----------------
template<int NROWS, bool INIT>
__global__ __launch_bounds__(1024)
void readout_kernel(const float* __restrict__ h, float* __restrict__ rout) {
    int b = blockIdx.x;
    int f = threadIdx.x & 255, c = threadIdx.x >> 8;   // 1024 threads: 4 row-chunks
    const float* hb = h + (size_t)b * NROWS * NH;
    float mx = -1e30f, sm = 0.f;
    for (int p = c; p < NROWS; p += 4) {
        float v = hb[(size_t)p * NH + f];
        mx = fmaxf(mx, v);
        sm += v;
    }
    __shared__ float rm[4][256], rs[4][256];
    rm[c][f] = mx; rs[c][f] = sm;
    __syncthreads();
    if (c == 0) {
        #pragma unroll
        for (int j = 1; j < 4; ++j) { mx = fmaxf(mx, rm[j][f]); sm += rs[j][f]; }
        float rmv = fmaxf(mx, 0.f);
        float rav = fmaxf(sm * (1.0f / NROWS), 0.f);
        if (INIT) { rout[b * 512 + f] = rmv;  rout[b * 512 + NH + f] = rav; }
        else      { rout[b * 512 + f] += rmv; rout[b * 512 + NH + f] += rav; }
    }
}

// ---------------- fused stage-3: h3 = relu(0.5*(a2@t3 + t3) + b3) -> readout += ----------------
// grid B*8: block covers all 256 rows x 32-col slice. 256 thr = 8 ct (4 cols) x 32 rt (8 rows)
__global__ __launch_bounds__(256, 2)
void gcn3_fused_kernel(const float* __restrict__ a2, const float* __restrict__ t3,
                       const float* __restrict__ b3, float* __restrict__ rout) {
    constexpr int KC = 16;
    __shared__ float sa[KC][260];            // padded: conflict-free staging
    __shared__ float st[KC][32];
    int b = blockIdx.x >> 3;
    int cb = (blockIdx.x & 7) * 32;
    int tid = threadIdx.x;
    int ct = tid & 7, rt = tid >> 3;
    int c0 = cb + ct * 4, r0 = rt * 8;
    const float* ab = a2 + (size_t)b * KP2 * KP2;
    const float* tb = t3 + (size_t)b * KP2 * NH;
    float acc[8][4] = {};
    for (int q0 = 0; q0 < KP2; q0 += KC) {
        const float4* A4 = (const float4*)ab;
        for (int i = tid; i < 256 * (KC / 4); i += 256) {
            int r = i >> 2, j = i & 3;
            float4 v = A4[(size_t)r * 64 + q0 / 4 + j];
            sa[j * 4 + 0][r] = v.x; sa[j * 4 + 1][r] = v.y;
            sa[j * 4 + 2][r] = v.z; sa[j * 4 + 3][r] = v.w;
        }
        if (tid < KC * 8) {
            int q = tid >> 3, c4 = tid & 7;
            *(float4*)&st[q][c4 * 4] = *(const float4*)&tb[(size_t)(q0 + q) * NH + cb + c4 * 4];
        }
        __syncthreads();
        #pragma unroll
        for (int q = 0; q < KC; ++q) {
            float tv[4], av[8];
            *(float4*)&tv[0] = *(const float4*)&st[q][ct * 4];
            *(float4*)&av[0] = *(const float4*)&sa[q][r0];
            *(float4*)&av[4] = *(const float4*)&sa[q][r0 + 4];
            #pragma unroll
            for (int r = 0; r < 8; ++r)
                #pragma unroll
                for (int c = 0; c < 4; ++c)
                    acc[r][c] += av[r] * tv[c];
        }
        __syncthreads();
    }
    float bv[4];
    *(float4*)&bv[0] = *(const float4*)&b3[c0];
    float mx[4] = {-1e30f, -1e30f, -1e30f, -1e30f}, sm[4] = {};
    for (int r = 0; r < 8; ++r) {
        float4 t4 = *(const float4*)&tb[(size_t)(r0 + r) * NH + c0];
        float tvv[4] = {t4.x, t4.y, t4.z, t4.w};
        #pragma unroll
        for (int c = 0; c < 4; ++c) {
            float h = fmaxf(0.5f * (acc[r][c] + tvv[c]) + bv[c], 0.f);
            mx[c] = fmaxf(mx[c], h);
            sm[c] += h;
        }
    }
    __shared__ float rmx[32][33], rsm[32][33];
    #pragma unroll
    for (int c = 0; c < 4; ++c) { rmx[ct * 4 + c][rt] = mx[c]; rsm[ct * 4 + c][rt] = sm[c]; }
    __syncthreads();
    if (tid < 32) {
        float m = -1e30f, s = 0.f;
        for (int r = 0; r < 32; ++r) { m = fmaxf(m, rmx[tid][r]); s += rsm[tid][r]; }
        rout[b * 512 + cb + tid] += fmaxf(m, 0.f);
        rout[b * 512 + NH + cb + tid] += fmaxf(s * (1.f / KP2), 0.f);
    }
}

// ---------------- final linear ----------------
__global__ __launch_bounds__(64)
void final_kernel(const float* __restrict__ rout, const float* __restrict__ Wlin,
                  const float* __restrict__ blin, float* __restrict__ out) {
    int b = blockIdx.x;
    int c = threadIdx.x;
    if (c < NCLS) {
        float acc = blin[c];
        for (int fidx = 0; fidx < 512; ++fidx)
            acc += rout[b * 512 + fidx] * Wlin[fidx * NCLS + c];
        out[b * NCLS + c] = acc;
    }
}

extern "C" void kernel_launch(void* const* d_in, const int* in_sizes, int n_in,
                              void* d_out, int out_size, void* d_ws, size_t ws_size,
                              hipStream_t stream) {
    const float* x    = (const float*)d_in[0];
    const float* adj  = (const float*)d_in[1];
    const float* W1   = (const float*)d_in[2];
    const float* b1   = (const float*)d_in[3];
    const float* W2   = (const float*)d_in[4];
    const float* b2   = (const float*)d_in[5];
    const float* W3   = (const float*)d_in[6];
    const float* b3   = (const float*)d_in[7];
    const float* att1 = (const float*)d_in[8];
    const float* att2 = (const float*)d_in[9];
    const float* Wlin = (const float*)d_in[10];
    const float* blin = (const float*)d_in[11];
    float* out = (float*)d_out;

    float* fws = (float*)d_ws;
    float* t1  = fws;                        // 8,388,608 floats
    float* h1  = t1 + 8388608;               // 8,388,608
    float* hk  = h1 + 8388608;               // 4,194,304
    float* dgi = hk + 4194304;               // 32768
    float* dia = dgi + 32768;
    float* sc  = dia + 32768;
    float* lv  = sc + 32768;                 // 16384
    float* rv  = lv + 16384;                 // 16384
    float* rout = rv + 16384;                // 16384
    float* v1  = rout + 16384;               // 16384
    float* V1  = v1 + 16384;                 // 64 (padded)
    float* Z1  = V1 + 64;                    // 16384
    float* wp  = Z1 + 16384;                 // 32*8*256 = 65536
    int* cnt  = (int*)(wp + 65536);          // 32768
    int* nbr  = cnt + 32768;                 // 32768*64 = 2,097,152
    int* idx1 = nbr + 32768 * MAXD;          // 16384
    int* idx2 = idx1 + 16384;                // 8192
    int* pos1 = idx2 + 8192;                 // 32768
    // aliases (lifetime-disjoint reuse)
    float* t2   = h1;                        // stage-2 XW   [B*KP1*NH]
    float* h2   = h1 + 4194304;              // stage-2 hidden
    float* h2k  = hk;                        // stage-2 pooled rows
    float* a2   = t1;                        // [B*KP2*KP2] = 2,097,152 (t1 dead after gcn1)
    float* t3   = t1 + 2097152;              // 2,097,152
    int*   knbr = (int*)(t1 + 6291456);      // 16384*64 = 1,048,576 ints
    int*   kcnt = knbr + 16384 * MAXD;       // 16384

    // ---- stage 1 (sparse binary graph) ----
    gemm_kernel<FIN, 64, 8><<<512, 256, 0, stream>>>(x, W1, t1);
    csr_kernel<<<B * N1, 256, 0, stream>>>(adj, cnt, nbr, dgi, dia);
    gcn1_kernel<<<B * N1, 256, 0, stream>>>(t1, cnt, nbr, dgi, b1, h1);
    info1_kernel<<<B * N1, 256, 0, stream>>>(h1, cnt, nbr, dia, sc);
    topk_kernel<N1, KP1, 512, true><<<B, 512, 0, stream>>>(sc, idx1, pos1);
    gather_att_kernel<<<B * KP1, 256, 0, stream>>>(h1, idx1, att1, hk, lv, rv, KP1, N1);
    readout_kernel<KP1, true><<<B, 1024, 0, stream>>>(hk, rout);

    // ---- pool-1 factorization: a1[p,q] = v_q*(1+E1*adjk)/Z_p ----
    vexp_kernel<<<B, 512, 0, stream>>>(rv, v1, V1);
    knbr_kernel<<<B * KP1, 64, 0, stream>>>(idx1, cnt, nbr, pos1, v1, V1, knbr, kcnt, Z1);

    // ---- stage 2 (factorized a1) ----
    gemm_kernel<NH, 64, 8><<<256, 256, 0, stream>>>(hk, W2, t2);
    wsum_kernel<<<B * 8, 256, 0, stream>>>(t2, v1, wp);
    gcn2_kernel<<<B * KP1, 256, 0, stream>>>(t2, wp, v1, Z1, knbr, kcnt, b2, h2);
    wsum_kernel<<<B * 8, 256, 0, stream>>>(h2, v1, wp);
    info2_kernel<<<B * KP1, 256, 0, stream>>>(h2, wp, v1, Z1, knbr, kcnt, sc);
    topk_kernel<KP1, KP2, 256, false><<<B, 256, 0, stream>>>(sc, idx2, nullptr);
    gather_att_kernel<<<B * KP2, 256, 0, stream>>>(h2, idx2, att2, h2k, lv, rv, KP2, KP1);
    readout_kernel<KP2, false><<<B, 1024, 0, stream>>>(h2k, rout);
    a2_kernel<<<B * KP2, 256, 0, stream>>>(idx2, rv, v1, Z1, knbr, kcnt, a2);

    // ---- stage 3 (fused dense GCN + readout) ----
    gemm_kernel<NH, 32, 4><<<256, 256, 0, stream>>>(h2k, W3, t3);
    gcn3_fused_kernel<<<B * 8, 256, 0, stream>>>(a2, t3, b3, rout);

    // ---- classifier ----
    final_kernel<<<B, 64, 0, stream>>>(rout, Wlin, blin, out);
}